// Round 7
// baseline (590.221 us; speedup 1.0000x reference)
//
#include <hip/hip_runtime.h>
#include <cstdint>

constexpr int B_ = 32, T_ = 32, N_ = 256, FIN = 32, FOUT = 32, H_ = 256;
constexpr int IN_ = N_ * FOUT;   // 8192
constexpr int G4  = 4 * H_;      // 1024
constexpr int BT  = B_ * T_;     // 1024
constexpr int KZ  = 16;          // split-K partials
constexpr int NPACK = 4100;      // pack blocks appended after gat blocks
#define NEG_SLOPE 0.2f

typedef _Float16 half8 __attribute__((ext_vector_type(8)));
typedef _Float16 h2    __attribute__((ext_vector_type(2)));
typedef float    f4    __attribute__((ext_vector_type(4)));

union U48 { uint4 u; half8 h; };

__device__ inline uint32_t pkh2(float a, float b) {
    union { uint32_t u; _Float16 h[2]; } z;
    z.h[0] = (_Float16)a; z.h[1] = (_Float16)b; return z.u;
}
__device__ inline float f16lo(uint32_t u){ union{uint32_t u; _Float16 h[2];} z; z.u=u; return (float)z.h[0]; }
__device__ inline float f16hi(uint32_t u){ union{uint32_t u; _Float16 h[2];} z; z.u=u; return (float)z.h[1]; }

__device__ inline float dot2f(uint32_t w, uint32_t h, float acc) {
    union { uint32_t u; h2 v; } a, b; a.u = w; b.u = h;
#if __has_builtin(__builtin_amdgcn_fdot2)
    return __builtin_amdgcn_fdot2(a.v, b.v, acc, false);
#else
    return acc + (float)a.v.x * (float)b.v.x + (float)a.v.y * (float)b.v.y;
#endif
}

__device__ inline void gload16(const void* g, void* l) {
    __builtin_amdgcn_global_load_lds(
        (const __attribute__((address_space(1))) void*)g,
        (__attribute__((address_space(3))) void*)l, 16, 0, 0);
}

// =====================================================================
// K1: merged GAT + pack. Blocks 0..1023: GAT for bt=blockIdx (dispatched
// FIRST so the HBM-bound phase starts at t=0). Blocks 1024..5119: W_ih
// f32->f16; blocks 5120..5123: W_hh f16x2 packs (co-run/tail under GAT).
// GAT: h=x@W -> hT[o][j] f16 (pad 264); adj column stream DOUBLE-BUFFERED
// in VGPRs (chunk c+1's 32 loads issued before chunk c's exp/Pc/MFMA);
// per-thread masked exp into XOR-swizzled K=32 P-chunks (43KB LDS ->
// 3 blocks/CU); O += Pc @ hT via MFMA. Wave's A-rows are its own threads'
// rows -> no barrier in the chunk loop; 1 barrier total.
// =====================================================================
__global__ __launch_bounds__(256) void gat_pack_kernel(
    const float* __restrict__ x, const float* __restrict__ adj,
    const float* __restrict__ W, const float* __restrict__ a_src,
    const float* __restrict__ a_dst, const float* __restrict__ gat_b,
    _Float16* __restrict__ seq,
    const float* __restrict__ Wih, const float* __restrict__ Whh,
    _Float16* __restrict__ wih_h, uint32_t* __restrict__ pwv,
    uint32_t* __restrict__ pwl, uint32_t* __restrict__ pws)
{
    if (blockIdx.x >= BT) {
        const int pid = blockIdx.x - BT;
        if (pid < 4096) {
            int idx = (pid * 256 + threadIdx.x) * 8;
            float4 v0 = *reinterpret_cast<const float4*>(Wih + idx);
            float4 v1 = *reinterpret_cast<const float4*>(Wih + idx + 4);
            half8 o;
            o[0]=(_Float16)v0.x; o[1]=(_Float16)v0.y; o[2]=(_Float16)v0.z; o[3]=(_Float16)v0.w;
            o[4]=(_Float16)v1.x; o[5]=(_Float16)v1.y; o[6]=(_Float16)v1.z; o[7]=(_Float16)v1.w;
            *reinterpret_cast<half8*>(wih_h + idx) = o;
        } else {
            int g = (pid - 4096) * 256 + threadIdx.x;
            const float* row = Whh + (size_t)g * H_;
            #pragma unroll
            for (int p = 0; p < 128; ++p) {
                float2 v = *reinterpret_cast<const float2*>(row + 2*p);
                uint32_t u = pkh2(v.x, v.y);
                if (p < 64) pwv[p * 1024 + g] = u;
                else if (p < 96) { int pp = p - 64; pwl[(pp >> 2) * 4096 + g * 4 + (pp & 3)] = u; }
                else             { int pp = p - 96; pws[(pp >> 2) * 4096 + g * 4 + (pp & 3)] = u; }
            }
        }
        return;
    }

    const int bt = blockIdx.x;
    const int i  = threadIdx.x;
    const int L  = i & 63, w = i >> 6;
    __shared__ float Ws[FIN * FOUT];
    __shared__ __align__(16) _Float16 hT[32 * 264];   // [o][j] pad 8
    __shared__ __align__(16) uint32_t Pc[256 * 20];   // [i][q] K=32 chunk, swizzled
    __shared__ float ssrc[N_];
    __shared__ float linv[N_];
    __shared__ float asv[FOUT], adv[FOUT], gbv[FOUT];

    for (int t = i; t < FIN * FOUT; t += 256) Ws[t] = W[t];
    if (i < FOUT) { asv[i] = a_src[i]; adv[i] = a_dst[i]; gbv[i] = gat_b[i]; }

    float xr[FIN];
    const float* xrow = x + ((size_t)bt * N_ + i) * FIN;
    #pragma unroll
    for (int f4i = 0; f4i < FIN / 4; ++f4i) {
        float4 v = reinterpret_cast<const float4*>(xrow)[f4i];
        xr[4*f4i] = v.x; xr[4*f4i+1] = v.y; xr[4*f4i+2] = v.z; xr[4*f4i+3] = v.w;
    }
    const float* adjcol = adj + (size_t)bt * N_ * N_ + i;
    // preload chunk 0 of the adj column stream (overlaps the h compute)
    float va[32];
    #pragma unroll
    for (int u = 0; u < 32; ++u) va[u] = adjcol[(size_t)u * N_];
    __syncthreads();

    float hr[FOUT];
    #pragma unroll
    for (int k4 = 0; k4 < FOUT / 4; ++k4) {
        float ax = 0.f, ay = 0.f, az = 0.f, aw = 0.f;
        #pragma unroll
        for (int f = 0; f < FIN; ++f) {
            float4 w4 = *reinterpret_cast<const float4*>(&Ws[f*FOUT + 4*k4]);
            ax += xr[f]*w4.x; ay += xr[f]*w4.y; az += xr[f]*w4.z; aw += xr[f]*w4.w;
        }
        hr[4*k4] = ax; hr[4*k4+1] = ay; hr[4*k4+2] = az; hr[4*k4+3] = aw;
    }
    float ss = 0.f, sd = 0.f;
    #pragma unroll
    for (int k = 0; k < FOUT; ++k) { ss += hr[k]*asv[k]; sd += hr[k]*adv[k]; }
    #pragma unroll
    for (int k = 0; k < FOUT; ++k) hT[k*264 + i] = (_Float16)hr[k];
    ssrc[i] = ss;
    __syncthreads();   // the ONLY barrier

    float l = 0.f;
    f4 acc[4][2] = {};                       // wave tiles: 4 i-tiles x 2 o-tiles
    const int key = (i >> 3) & 3;
    const int m = L & 15, G = L >> 4;

    #pragma unroll
    for (int c = 0; c < 8; ++c) {
        // issue next chunk's loads before touching this chunk's values
        float vb[32];
        if (c < 7) {
            const int jn = (c + 1) * 32;
            #pragma unroll
            for (int u = 0; u < 32; ++u) vb[u] = adjcol[(size_t)(jn + u) * N_];
        }
        const int j0 = c * 32;
        #pragma unroll
        for (int q = 0; q < 16; ++q) {
            int ja = j0 + 2*q, jb = ja + 1;
            float e0 = sd + ssrc[ja]; e0 = e0 > 0.f ? e0 : NEG_SLOPE * e0;
            float e1 = sd + ssrc[jb]; e1 = e1 > 0.f ? e1 : NEG_SLOPE * e1;
            float p0 = ((va[2*q] != 0.f)   || (ja == i)) ? __expf(e0) : 0.f;
            float p1 = ((va[2*q+1] != 0.f) || (jb == i)) ? __expf(e1) : 0.f;
            l += p0 + p1;
            Pc[i*20 + (((q >> 2) ^ key) << 2) + (q & 3)] = pkh2(p0, p1);
        }
        U48 b0, b1;
        b0.h = *reinterpret_cast<const half8*>(&hT[m*264      + j0 + G*8]);
        b1.h = *reinterpret_cast<const half8*>(&hT[(m+16)*264 + j0 + G*8]);
        #pragma unroll
        for (int it = 0; it < 4; ++it) {
            int row = w*64 + it*16 + m;
            int rkey = (row >> 3) & 3;
            U48 a;
            a.u = reinterpret_cast<const uint4*>(&Pc[row*20])[G ^ rkey];
            acc[it][0] = __builtin_amdgcn_mfma_f32_16x16x32_f16(a.h, b0.h, acc[it][0], 0, 0, 0);
            acc[it][1] = __builtin_amdgcn_mfma_f32_16x16x32_f16(a.h, b1.h, acc[it][1], 0, 0, 0);
        }
        if (c < 7) {
            #pragma unroll
            for (int u = 0; u < 32; ++u) va[u] = vb[u];
        }
    }
    linv[i] = 1.f / l;   // self-loop guarantees l > 0
    _Float16* obase = seq + (size_t)bt * IN_;
    #pragma unroll
    for (int it = 0; it < 4; ++it) {
        int ib = w*64 + it*16 + G*4;
        #pragma unroll
        for (int ot = 0; ot < 2; ++ot) {
            int o = ot*16 + m;
            float gb = gbv[o];
            #pragma unroll
            for (int r = 0; r < 4; ++r) {
                int row = ib + r;
                obase[row * FOUT + o] = (_Float16)(acc[it][ot][r] * linv[row] + gb);
            }
        }
    }
}

// =====================================================================
// K3: f16 MFMA GEMM  Gp[z][m=bt][n] = A[m][k] * B[n][k] over k-slice z.
// 128x128 tile, BK=32, split-K=16 (1024 blocks -> 4/CU for latency
// hiding) into SEPARATE partials: plain stores, no atomics, no pre-zero.
// =====================================================================
__global__ __launch_bounds__(256, 4) void gemm_kernel(
    const _Float16* __restrict__ A, const _Float16* __restrict__ Bh,
    float* __restrict__ Gp)
{
    __shared__ __align__(16) _Float16 As[128 * 32];
    __shared__ __align__(16) _Float16 Bs[128 * 32];
    const int t = threadIdx.x;
    const int L = t & 63, w = t >> 6;
    const int wm = w & 1, wn = w >> 1;
    const int m0 = blockIdx.y * 128, n0 = blockIdx.x * 128;
    const int kz = blockIdx.z * (IN_ / KZ);   // 512-wide k-slice

    f4 acc[4][4] = {};
    const int q0 = t, q1 = t + 256;
    const int row0 = q0 >> 2, kc0 = q0 & 3;
    const int row1 = q1 >> 2, kc1 = q1 & 3;
    const int la = (L & 15) * 32 + (L >> 4) * 8;

    const _Float16* A0 = A + (size_t)(m0 + row0) * IN_ + kz + kc0 * 8;
    const _Float16* A1 = A + (size_t)(m0 + row1) * IN_ + kz + kc1 * 8;
    const _Float16* B0 = Bh + (size_t)(n0 + row0) * IN_ + kz + kc0 * 8;
    const _Float16* B1 = Bh + (size_t)(n0 + row1) * IN_ + kz + kc1 * 8;
    for (int kb = 0; kb < IN_ / KZ; kb += 32) {
        __syncthreads();
        gload16(A0 + kb, &As[q0 * 8]);
        gload16(A1 + kb, &As[q1 * 8]);
        gload16(B0 + kb, &Bs[q0 * 8]);
        gload16(B1 + kb, &Bs[q1 * 8]);
        __syncthreads();
        half8 af[4], bf[4];
        #pragma unroll
        for (int mi = 0; mi < 4; ++mi)
            af[mi] = *reinterpret_cast<const half8*>(&As[(wm*64 + mi*16) * 32 + la]);
        #pragma unroll
        for (int ni = 0; ni < 4; ++ni)
            bf[ni] = *reinterpret_cast<const half8*>(&Bs[(wn*64 + ni*16) * 32 + la]);
        #pragma unroll
        for (int mi = 0; mi < 4; ++mi)
            #pragma unroll
            for (int ni = 0; ni < 4; ++ni)
                acc[mi][ni] = __builtin_amdgcn_mfma_f32_16x16x32_f16(
                    af[mi], bf[ni], acc[mi][ni], 0, 0, 0);
    }
    float* Gz = Gp + (size_t)blockIdx.z * BT * G4;
    const int cn = n0 + wn * 64 + (L & 15);
    const int rm = m0 + wm * 64 + (L >> 4) * 4;
    #pragma unroll
    for (int mi = 0; mi < 4; ++mi)
        #pragma unroll
        for (int ni = 0; ni < 4; ++ni)
            #pragma unroll
            for (int r = 0; r < 4; ++r)
                Gz[(size_t)(rm + mi*16 + r) * G4 + cn + ni*16] = acc[mi][ni][r];
}

// =====================================================================
// K4: LSTM recurrence + output linear. Block per b, thread = gate row.
// Gate preactivation = bias + sum of 16 split-K partials (prefetched one
// timestep ahead, overlapped with the dot2 chain).
// W_hh row (128 f16x2 packs): 64 VGPR + 32 LDS (128KB) + 32 streamed (L2).
// =====================================================================
__global__ __launch_bounds__(1024) void lstm_kernel(
    const float* __restrict__ Gp, const uint32_t* __restrict__ pwv,
    const uint32_t* __restrict__ pwl, const uint32_t* __restrict__ pws,
    const float* __restrict__ b_ih, const float* __restrict__ b_hh,
    const float* __restrict__ Wo, const float* __restrict__ bo,
    float* __restrict__ out)
{
    const int b = blockIdx.x;
    const int g = threadIdx.x;
    __shared__ __align__(16) uint32_t hsp[128];      // h as f16x2
    __shared__ float gsh[G4];
    __shared__ __align__(16) uint32_t wl[8 * 4096];  // 32 packs x 1024 = 128KB

    uint32_t wv[64];
    #pragma unroll
    for (int p = 0; p < 64; ++p) wv[p] = pwv[p * 1024 + g];
    {
        const uint4* s = reinterpret_cast<const uint4*>(pwl);
        uint4* d = reinterpret_cast<uint4*>(wl);
        #pragma unroll
        for (int r = 0; r < 8; ++r) d[r * 1024 + g] = s[r * 1024 + g];
    }
    if (g < 128) hsp[g] = 0u;
    float c = 0.f;
    const float bias = b_ih[g] + b_hh[g];
    const size_t zs = (size_t)BT * G4;
    const float* Gb = Gp + (size_t)b * T_ * G4 + g;
    const uint4* pws4 = reinterpret_cast<const uint4*>(pws);
    const uint4* wl4  = reinterpret_cast<const uint4*>(wl);
    const uint4* hsp4 = reinterpret_cast<const uint4*>(hsp);

    float gcur = 0.f;
    #pragma unroll
    for (int z = 0; z < KZ; ++z) gcur += Gb[z * zs];
    __syncthreads();

    for (int t = 0; t < T_; ++t) {
        float acc = bias + gcur;
        float pf[KZ];
        const int tn = (t + 1 < T_) ? t + 1 : t;   // harmless dup on last iter
        #pragma unroll
        for (int z = 0; z < KZ; ++z) pf[z] = Gb[(size_t)tn * G4 + z * zs];
        #pragma unroll
        for (int q = 0; q < 32; ++q) {
            uint4 h4 = hsp4[q];
            uint4 w4;
            if (q < 16) {
                w4.x = wv[4*q]; w4.y = wv[4*q+1]; w4.z = wv[4*q+2]; w4.w = wv[4*q+3];
            } else if (q < 24) {
                w4 = wl4[(q - 16) * 1024 + g];
            } else {
                w4 = pws4[(q - 24) * 1024 + g];
            }
            acc = dot2f(w4.x, h4.x, acc);
            acc = dot2f(w4.y, h4.y, acc);
            acc = dot2f(w4.z, h4.z, acc);
            acc = dot2f(w4.w, h4.w, acc);
        }
        {   // pairwise deterministic sum of 16 partials
            float s01 = pf[0]+pf[1],   s23 = pf[2]+pf[3];
            float s45 = pf[4]+pf[5],   s67 = pf[6]+pf[7];
            float s89 = pf[8]+pf[9],   sab = pf[10]+pf[11];
            float scd = pf[12]+pf[13], sef = pf[14]+pf[15];
            gcur = ((s01+s23) + (s45+s67)) + ((s89+sab) + (scd+sef));
        }
        gsh[g] = acc;
        __syncthreads();
        if (g < H_) {
            float xi = gsh[g], xf = gsh[H_ + g], xg = gsh[2*H_ + g], xo = gsh[3*H_ + g];
            float si = 1.f / (1.f + __expf(-xi));
            float sf = 1.f / (1.f + __expf(-xf));
            float so = 1.f / (1.f + __expf(-xo));
            float eg = __expf(2.f * xg);
            float tg = 1.f - 2.f / (eg + 1.f);
            c = sf * c + si * tg;
            float ec = __expf(2.f * c);
            float th = 1.f - 2.f / (ec + 1.f);
            reinterpret_cast<_Float16*>(hsp)[g] = (_Float16)(so * th);
        }
        __syncthreads();
    }
    if (g < N_) {
        const float* worow = Wo + (size_t)g * H_;
        float o = bo[g];
        #pragma unroll
        for (int q = 0; q < 32; ++q) {
            uint4 hq = hsp4[q];
            float4 w0 = *reinterpret_cast<const float4*>(worow + q*8);
            float4 w1 = *reinterpret_cast<const float4*>(worow + q*8 + 4);
            o += w0.x * f16lo(hq.x) + w0.y * f16hi(hq.x)
               + w0.z * f16lo(hq.y) + w0.w * f16hi(hq.y)
               + w1.x * f16lo(hq.z) + w1.y * f16hi(hq.z)
               + w1.z * f16lo(hq.w) + w1.w * f16hi(hq.w);
        }
        out[(size_t)b * N_ + g] = o;
    }
}

extern "C" void kernel_launch(void* const* d_in, const int* in_sizes, int n_in,
                              void* d_out, int out_size, void* d_ws, size_t ws_size,
                              hipStream_t stream) {
    const float* x     = (const float*)d_in[0];
    const float* adj   = (const float*)d_in[1];
    const float* W     = (const float*)d_in[2];
    const float* a_src = (const float*)d_in[3];
    const float* a_dst = (const float*)d_in[4];
    const float* gat_b = (const float*)d_in[5];
    const float* W_ih  = (const float*)d_in[6];
    const float* W_hh  = (const float*)d_in[7];
    const float* b_ih  = (const float*)d_in[8];
    const float* b_hh  = (const float*)d_in[9];
    const float* Wo    = (const float*)d_in[10];
    const float* bo    = (const float*)d_in[11];
    float* out = (float*)d_out;

    // ws: seq 16MB | wih_h 16MB | Gp 64MB (16 partials) | pwv 256KB | pwl 128KB | pws 128KB
    _Float16* seq   = (_Float16*)d_ws;
    _Float16* wih_h = seq + (size_t)BT * IN_;
    float*    Gp    = (float*)(wih_h + (size_t)G4 * IN_);
    uint32_t* pwv   = (uint32_t*)(Gp + (size_t)KZ * BT * G4);
    uint32_t* pwl   = pwv + 64 * 1024;
    uint32_t* pws   = pwl + 32 * 1024;

    gat_pack_kernel<<<dim3(BT + NPACK), dim3(256), 0, stream>>>(
        x, adj, W, a_src, a_dst, gat_b, seq, W_ih, W_hh, wih_h, pwv, pwl, pws);
    gemm_kernel<<<dim3(8, 8, KZ), dim3(256), 0, stream>>>(seq, wih_h, Gp);
    lstm_kernel<<<dim3(B_), dim3(1024), 0, stream>>>(Gp, pwv, pwl, pws, b_ih, b_hh, Wo, bo, out);
}

// Round 8
// 545.026 us; speedup vs baseline: 1.0829x; 1.0829x over previous
//
#include <hip/hip_runtime.h>
#include <cstdint>

constexpr int B_ = 32, T_ = 32, N_ = 256, FIN = 32, FOUT = 32, H_ = 256;
constexpr int IN_ = N_ * FOUT;   // 8192
constexpr int G4  = 4 * H_;      // 1024
constexpr int BT  = B_ * T_;     // 1024
constexpr int KZ  = 8;           // split-K partials
constexpr int NPACK = 4100;      // pack blocks appended after gat blocks
#define NEG_SLOPE 0.2f

typedef _Float16 half8 __attribute__((ext_vector_type(8)));
typedef _Float16 h2    __attribute__((ext_vector_type(2)));
typedef float    f4    __attribute__((ext_vector_type(4)));

union U48 { uint4 u; half8 h; };

__device__ inline uint32_t pkh2(float a, float b) {
    union { uint32_t u; _Float16 h[2]; } z;
    z.h[0] = (_Float16)a; z.h[1] = (_Float16)b; return z.u;
}
__device__ inline float f16lo(uint32_t u){ union{uint32_t u; _Float16 h[2];} z; z.u=u; return (float)z.h[0]; }
__device__ inline float f16hi(uint32_t u){ union{uint32_t u; _Float16 h[2];} z; z.u=u; return (float)z.h[1]; }

__device__ inline float dot2f(uint32_t w, uint32_t h, float acc) {
    union { uint32_t u; h2 v; } a, b; a.u = w; b.u = h;
#if __has_builtin(__builtin_amdgcn_fdot2)
    return __builtin_amdgcn_fdot2(a.v, b.v, acc, false);
#else
    return acc + (float)a.v.x * (float)b.v.x + (float)a.v.y * (float)b.v.y;
#endif
}

__device__ inline void gload16(const void* g, void* l) {
    __builtin_amdgcn_global_load_lds(
        (const __attribute__((address_space(1))) void*)g,
        (__attribute__((address_space(3))) void*)l, 16, 0, 0);
}

// =====================================================================
// K1: merged GAT + pack. Blocks 0..1023: GAT for bt=blockIdx (dispatched
// FIRST so the HBM-bound phase starts at t=0). Blocks 1024..5119: W_ih
// f32->f16; blocks 5120..5123: W_hh f16x2 packs (fill CU slots as GAT
// blocks retire). GAT body = round-6 structure: K=32 P-chunks, loads
// issued inside the q-loop (no VGPR double-buffer -> stays under the
// 128-VGPR tier, 3 blocks/CU). 1 barrier total.
// =====================================================================
__global__ __launch_bounds__(256) void gat_pack_kernel(
    const float* __restrict__ x, const float* __restrict__ adj,
    const float* __restrict__ W, const float* __restrict__ a_src,
    const float* __restrict__ a_dst, const float* __restrict__ gat_b,
    _Float16* __restrict__ seq,
    const float* __restrict__ Wih, const float* __restrict__ Whh,
    _Float16* __restrict__ wih_h, uint32_t* __restrict__ pwv,
    uint32_t* __restrict__ pwl, uint32_t* __restrict__ pws)
{
    if (blockIdx.x >= BT) {
        const int pid = blockIdx.x - BT;
        if (pid < 4096) {
            int idx = (pid * 256 + threadIdx.x) * 8;
            float4 v0 = *reinterpret_cast<const float4*>(Wih + idx);
            float4 v1 = *reinterpret_cast<const float4*>(Wih + idx + 4);
            half8 o;
            o[0]=(_Float16)v0.x; o[1]=(_Float16)v0.y; o[2]=(_Float16)v0.z; o[3]=(_Float16)v0.w;
            o[4]=(_Float16)v1.x; o[5]=(_Float16)v1.y; o[6]=(_Float16)v1.z; o[7]=(_Float16)v1.w;
            *reinterpret_cast<half8*>(wih_h + idx) = o;
        } else {
            int g = (pid - 4096) * 256 + threadIdx.x;
            const float* row = Whh + (size_t)g * H_;
            #pragma unroll
            for (int p = 0; p < 128; ++p) {
                float2 v = *reinterpret_cast<const float2*>(row + 2*p);
                uint32_t u = pkh2(v.x, v.y);
                if (p < 64) pwv[p * 1024 + g] = u;
                else if (p < 96) { int pp = p - 64; pwl[(pp >> 2) * 4096 + g * 4 + (pp & 3)] = u; }
                else             { int pp = p - 96; pws[(pp >> 2) * 4096 + g * 4 + (pp & 3)] = u; }
            }
        }
        return;
    }

    const int bt = blockIdx.x;
    const int i  = threadIdx.x;
    const int L  = i & 63, w = i >> 6;
    __shared__ float Ws[FIN * FOUT];
    __shared__ __align__(16) _Float16 hT[32 * 264];   // [o][j] pad 8
    __shared__ __align__(16) uint32_t Pc[256 * 20];   // [i][q] K=32 chunk, swizzled
    __shared__ float ssrc[N_];
    __shared__ float linv[N_];
    __shared__ float asv[FOUT], adv[FOUT], gbv[FOUT];

    for (int t = i; t < FIN * FOUT; t += 256) Ws[t] = W[t];
    if (i < FOUT) { asv[i] = a_src[i]; adv[i] = a_dst[i]; gbv[i] = gat_b[i]; }

    float xr[FIN];
    const float* xrow = x + ((size_t)bt * N_ + i) * FIN;
    #pragma unroll
    for (int f4i = 0; f4i < FIN / 4; ++f4i) {
        float4 v = reinterpret_cast<const float4*>(xrow)[f4i];
        xr[4*f4i] = v.x; xr[4*f4i+1] = v.y; xr[4*f4i+2] = v.z; xr[4*f4i+3] = v.w;
    }
    __syncthreads();

    float hr[FOUT];
    #pragma unroll
    for (int k4 = 0; k4 < FOUT / 4; ++k4) {
        float ax = 0.f, ay = 0.f, az = 0.f, aw = 0.f;
        #pragma unroll
        for (int f = 0; f < FIN; ++f) {
            float4 w4 = *reinterpret_cast<const float4*>(&Ws[f*FOUT + 4*k4]);
            ax += xr[f]*w4.x; ay += xr[f]*w4.y; az += xr[f]*w4.z; aw += xr[f]*w4.w;
        }
        hr[4*k4] = ax; hr[4*k4+1] = ay; hr[4*k4+2] = az; hr[4*k4+3] = aw;
    }
    float ss = 0.f, sd = 0.f;
    #pragma unroll
    for (int k = 0; k < FOUT; ++k) { ss += hr[k]*asv[k]; sd += hr[k]*adv[k]; }
    #pragma unroll
    for (int k = 0; k < FOUT; ++k) hT[k*264 + i] = (_Float16)hr[k];
    ssrc[i] = ss;
    __syncthreads();   // the ONLY barrier

    float l = 0.f;
    f4 acc[4][2] = {};                       // wave tiles: 4 i-tiles x 2 o-tiles
    const float* adjcol = adj + (size_t)bt * N_ * N_ + i;
    const int key = (i >> 3) & 3;
    const int m = L & 15, G = L >> 4;

    for (int c = 0; c < 8; ++c) {
        const int j0 = c * 32;
        #pragma unroll
        for (int q = 0; q < 16; ++q) {
            int ja = j0 + 2*q, jb = ja + 1;
            float a0 = adjcol[(size_t)ja * N_];
            float a1 = adjcol[(size_t)jb * N_];
            float e0 = sd + ssrc[ja]; e0 = e0 > 0.f ? e0 : NEG_SLOPE * e0;
            float e1 = sd + ssrc[jb]; e1 = e1 > 0.f ? e1 : NEG_SLOPE * e1;
            float p0 = ((a0 != 0.f) || (ja == i)) ? __expf(e0) : 0.f;
            float p1 = ((a1 != 0.f) || (jb == i)) ? __expf(e1) : 0.f;
            l += p0 + p1;
            Pc[i*20 + (((q >> 2) ^ key) << 2) + (q & 3)] = pkh2(p0, p1);
        }
        U48 b0, b1;
        b0.h = *reinterpret_cast<const half8*>(&hT[m*264      + j0 + G*8]);
        b1.h = *reinterpret_cast<const half8*>(&hT[(m+16)*264 + j0 + G*8]);
        #pragma unroll
        for (int it = 0; it < 4; ++it) {
            int row = w*64 + it*16 + m;
            int rkey = (row >> 3) & 3;
            U48 a;
            a.u = reinterpret_cast<const uint4*>(&Pc[row*20])[G ^ rkey];
            acc[it][0] = __builtin_amdgcn_mfma_f32_16x16x32_f16(a.h, b0.h, acc[it][0], 0, 0, 0);
            acc[it][1] = __builtin_amdgcn_mfma_f32_16x16x32_f16(a.h, b1.h, acc[it][1], 0, 0, 0);
        }
    }
    linv[i] = 1.f / l;   // self-loop guarantees l > 0
    _Float16* obase = seq + (size_t)bt * IN_;
    #pragma unroll
    for (int it = 0; it < 4; ++it) {
        int ib = w*64 + it*16 + G*4;
        #pragma unroll
        for (int ot = 0; ot < 2; ++ot) {
            int o = ot*16 + m;
            float gb = gbv[o];
            #pragma unroll
            for (int r = 0; r < 4; ++r) {
                int row = ib + r;
                obase[row * FOUT + o] = (_Float16)(acc[it][ot][r] * linv[row] + gb);
            }
        }
    }
}

// =====================================================================
// K3: f16 MFMA GEMM  Gp[z][m=bt][n] = A[m][k] * B[n][k] over k-slice z.
// 128x128 tile, BK=32, split-K=8 into SEPARATE partials: plain stores,
// no atomics, no pre-zero. LSTM sums the 8 partials.
// =====================================================================
__global__ __launch_bounds__(256, 4) void gemm_kernel(
    const _Float16* __restrict__ A, const _Float16* __restrict__ Bh,
    float* __restrict__ Gp)
{
    __shared__ __align__(16) _Float16 As[128 * 32];
    __shared__ __align__(16) _Float16 Bs[128 * 32];
    const int t = threadIdx.x;
    const int L = t & 63, w = t >> 6;
    const int wm = w & 1, wn = w >> 1;
    const int m0 = blockIdx.y * 128, n0 = blockIdx.x * 128;
    const int kz = blockIdx.z * 1024;

    f4 acc[4][4] = {};
    const int q0 = t, q1 = t + 256;
    const int row0 = q0 >> 2, kc0 = q0 & 3;
    const int row1 = q1 >> 2, kc1 = q1 & 3;
    const int la = (L & 15) * 32 + (L >> 4) * 8;

    const _Float16* A0 = A + (size_t)(m0 + row0) * IN_ + kz + kc0 * 8;
    const _Float16* A1 = A + (size_t)(m0 + row1) * IN_ + kz + kc1 * 8;
    const _Float16* B0 = Bh + (size_t)(n0 + row0) * IN_ + kz + kc0 * 8;
    const _Float16* B1 = Bh + (size_t)(n0 + row1) * IN_ + kz + kc1 * 8;
    for (int kb = 0; kb < 1024; kb += 32) {
        __syncthreads();
        gload16(A0 + kb, &As[q0 * 8]);
        gload16(A1 + kb, &As[q1 * 8]);
        gload16(B0 + kb, &Bs[q0 * 8]);
        gload16(B1 + kb, &Bs[q1 * 8]);
        __syncthreads();
        half8 af[4], bf[4];
        #pragma unroll
        for (int mi = 0; mi < 4; ++mi)
            af[mi] = *reinterpret_cast<const half8*>(&As[(wm*64 + mi*16) * 32 + la]);
        #pragma unroll
        for (int ni = 0; ni < 4; ++ni)
            bf[ni] = *reinterpret_cast<const half8*>(&Bs[(wn*64 + ni*16) * 32 + la]);
        #pragma unroll
        for (int mi = 0; mi < 4; ++mi)
            #pragma unroll
            for (int ni = 0; ni < 4; ++ni)
                acc[mi][ni] = __builtin_amdgcn_mfma_f32_16x16x32_f16(
                    af[mi], bf[ni], acc[mi][ni], 0, 0, 0);
    }
    float* Gz = Gp + (size_t)blockIdx.z * BT * G4;
    const int cn = n0 + wn * 64 + (L & 15);
    const int rm = m0 + wm * 64 + (L >> 4) * 4;
    #pragma unroll
    for (int mi = 0; mi < 4; ++mi)
        #pragma unroll
        for (int ni = 0; ni < 4; ++ni)
            #pragma unroll
            for (int r = 0; r < 4; ++r)
                Gz[(size_t)(rm + mi*16 + r) * G4 + cn + ni*16] = acc[mi][ni][r];
}

// =====================================================================
// K4: LSTM recurrence + output linear. Block per b, thread = gate row.
// Gate preactivation = bias + sum of 8 split-K partials (prefetched one
// timestep ahead, overlapped with the dot2 chain).
// W_hh row (128 f16x2 packs): 64 VGPR + 32 LDS (128KB) + 32 streamed (L2).
// =====================================================================
__global__ __launch_bounds__(1024) void lstm_kernel(
    const float* __restrict__ Gp, const uint32_t* __restrict__ pwv,
    const uint32_t* __restrict__ pwl, const uint32_t* __restrict__ pws,
    const float* __restrict__ b_ih, const float* __restrict__ b_hh,
    const float* __restrict__ Wo, const float* __restrict__ bo,
    float* __restrict__ out)
{
    const int b = blockIdx.x;
    const int g = threadIdx.x;
    __shared__ __align__(16) uint32_t hsp[128];      // h as f16x2
    __shared__ float gsh[G4];
    __shared__ __align__(16) uint32_t wl[8 * 4096];  // 32 packs x 1024 = 128KB

    uint32_t wv[64];
    #pragma unroll
    for (int p = 0; p < 64; ++p) wv[p] = pwv[p * 1024 + g];
    {
        const uint4* s = reinterpret_cast<const uint4*>(pwl);
        uint4* d = reinterpret_cast<uint4*>(wl);
        #pragma unroll
        for (int r = 0; r < 8; ++r) d[r * 1024 + g] = s[r * 1024 + g];
    }
    if (g < 128) hsp[g] = 0u;
    float c = 0.f;
    const float bias = b_ih[g] + b_hh[g];
    const size_t zs = (size_t)BT * G4;
    const float* Gb = Gp + (size_t)b * T_ * G4 + g;
    const uint4* pws4 = reinterpret_cast<const uint4*>(pws);
    const uint4* wl4  = reinterpret_cast<const uint4*>(wl);
    const uint4* hsp4 = reinterpret_cast<const uint4*>(hsp);

    float gcur = 0.f;
    #pragma unroll
    for (int z = 0; z < KZ; ++z) gcur += Gb[z * zs];
    __syncthreads();

    for (int t = 0; t < T_; ++t) {
        float acc = bias + gcur;
        float pf[KZ];
        const int tn = (t + 1 < T_) ? t + 1 : t;   // harmless dup on last iter
        #pragma unroll
        for (int z = 0; z < KZ; ++z) pf[z] = Gb[(size_t)tn * G4 + z * zs];
        #pragma unroll
        for (int q = 0; q < 32; ++q) {
            uint4 h4 = hsp4[q];
            uint4 w4;
            if (q < 16) {
                w4.x = wv[4*q]; w4.y = wv[4*q+1]; w4.z = wv[4*q+2]; w4.w = wv[4*q+3];
            } else if (q < 24) {
                w4 = wl4[(q - 16) * 1024 + g];
            } else {
                w4 = pws4[(q - 24) * 1024 + g];
            }
            acc = dot2f(w4.x, h4.x, acc);
            acc = dot2f(w4.y, h4.y, acc);
            acc = dot2f(w4.z, h4.z, acc);
            acc = dot2f(w4.w, h4.w, acc);
        }
        gcur = ((pf[0]+pf[1]) + (pf[2]+pf[3])) + ((pf[4]+pf[5]) + (pf[6]+pf[7]));
        gsh[g] = acc;
        __syncthreads();
        if (g < H_) {
            float xi = gsh[g], xf = gsh[H_ + g], xg = gsh[2*H_ + g], xo = gsh[3*H_ + g];
            float si = 1.f / (1.f + __expf(-xi));
            float sf = 1.f / (1.f + __expf(-xf));
            float so = 1.f / (1.f + __expf(-xo));
            float eg = __expf(2.f * xg);
            float tg = 1.f - 2.f / (eg + 1.f);
            c = sf * c + si * tg;
            float ec = __expf(2.f * c);
            float th = 1.f - 2.f / (ec + 1.f);
            reinterpret_cast<_Float16*>(hsp)[g] = (_Float16)(so * th);
        }
        __syncthreads();
    }
    if (g < N_) {
        const float* worow = Wo + (size_t)g * H_;
        float o = bo[g];
        #pragma unroll
        for (int q = 0; q < 32; ++q) {
            uint4 hq = hsp4[q];
            float4 w0 = *reinterpret_cast<const float4*>(worow + q*8);
            float4 w1 = *reinterpret_cast<const float4*>(worow + q*8 + 4);
            o += w0.x * f16lo(hq.x) + w0.y * f16hi(hq.x)
               + w0.z * f16lo(hq.y) + w0.w * f16hi(hq.y)
               + w1.x * f16lo(hq.z) + w1.y * f16hi(hq.z)
               + w1.z * f16lo(hq.w) + w1.w * f16hi(hq.w);
        }
        out[(size_t)b * N_ + g] = o;
    }
}

extern "C" void kernel_launch(void* const* d_in, const int* in_sizes, int n_in,
                              void* d_out, int out_size, void* d_ws, size_t ws_size,
                              hipStream_t stream) {
    const float* x     = (const float*)d_in[0];
    const float* adj   = (const float*)d_in[1];
    const float* W     = (const float*)d_in[2];
    const float* a_src = (const float*)d_in[3];
    const float* a_dst = (const float*)d_in[4];
    const float* gat_b = (const float*)d_in[5];
    const float* W_ih  = (const float*)d_in[6];
    const float* W_hh  = (const float*)d_in[7];
    const float* b_ih  = (const float*)d_in[8];
    const float* b_hh  = (const float*)d_in[9];
    const float* Wo    = (const float*)d_in[10];
    const float* bo    = (const float*)d_in[11];
    float* out = (float*)d_out;

    // ws: seq 16MB | wih_h 16MB | Gp 32MB (8 partials) | pwv 256KB | pwl 128KB | pws 128KB
    _Float16* seq   = (_Float16*)d_ws;
    _Float16* wih_h = seq + (size_t)BT * IN_;
    float*    Gp    = (float*)(wih_h + (size_t)G4 * IN_);
    uint32_t* pwv   = (uint32_t*)(Gp + (size_t)KZ * BT * G4);
    uint32_t* pwl   = pwv + 64 * 1024;
    uint32_t* pws   = pwl + 32 * 1024;

    gat_pack_kernel<<<dim3(BT + NPACK), dim3(256), 0, stream>>>(
        x, adj, W, a_src, a_dst, gat_b, seq, W_ih, W_hh, wih_h, pwv, pwl, pws);
    gemm_kernel<<<dim3(8, 8, KZ), dim3(256), 0, stream>>>(seq, wih_h, Gp);
    lstm_kernel<<<dim3(B_), dim3(1024), 0, stream>>>(Gp, pwv, pwl, pws, b_ih, b_hh, Wo, bo, out);
}